// Round 4
// baseline (90.439 us; speedup 1.0000x reference)
//
#include <hip/hip_runtime.h>
#include <utility>

#define BATCH 32768
#define NPHI 35
#define SWEEPS 6

// ---------- compile-time combinatorics ----------
constexpr int choose2(int n){ return (n*(n-1))/2; }

constexpr int tri_id_sorted(int a,int b,int c){
  int id=0;
  for(int x=0;x<a;++x) id += choose2(6-x);
  for(int y=a+1;y<b;++y) id += (6-y);
  id += (c-b-1);
  return id;
}

constexpr int tri_id3(int a,int b,int c){
  int x=a,y=b,z=c;
  if (x>y){int t=x;x=y;y=t;}
  if (y>z){int t=y;y=z;z=t;}
  if (x>y){int t=x;x=y;y=t;}
  return tri_id_sorted(x,y,z);
}

constexpr int sgn3(int a,int b,int c){
  int inv = (a>b)+(a>c)+(b>c);
  return (inv&1)? -1 : 1;
}

constexpr int UT(int i,int j){
  return i*7 - (i*(i-1))/2 + (j-i);
}

constexpr int pair_k(int g){
  int idx=0;
  for(int k=0;k<7;++k) for(int l=k+1;l<7;++l){ if(idx==g) return k; ++idx; }
  return 0;
}
constexpr int pair_l(int g){
  int idx=0;
  for(int k=0;k<7;++k) for(int l=k+1;l<7;++l){ if(idx==g) return l; ++idx; }
  return 0;
}

// ---------- per-(k,l)-group straight-line program ----------
struct GProg {
  int nt, nb;
  signed char t_dst[50], t_a[50], t_b[50], t_s[50]; unsigned char t_init[50];
  signed char b_dst[26], b_a[26], b_b[26], b_s[26];
};

constexpr GProg build_group(int k,int l){
  GProg P{}; P.nt=0; P.nb=0;
  bool tinit[7]={};
  for(int m=0;m<7;++m) for(int n2=m+1;n2<7;++n2){
    if(m==k||m==l||n2==k||n2==l) continue;
    int comp[3]={0,0,0}; int cn=0;
    for(int x=0;x<7;++x) if(x!=k&&x!=l&&x!=m&&x!=n2){ comp[cn]=x; ++cn; }
    int perm[7]={k,l,m,n2,comp[0],comp[1],comp[2]};
    int invc=0;
    for(int i=0;i<7;++i) for(int j=i+1;j<7;++j) if(perm[i]>perm[j]) ++invc;
    const int es=(invc&1)? -1 : 1;
    const int tcomp=tri_id_sorted(comp[0],comp[1],comp[2]);
    for(int j=0;j<7;++j){
      if(j==m||j==n2) continue;
      P.t_dst[P.nt]=(signed char)j;
      P.t_a [P.nt]=(signed char)tcomp;
      P.t_b [P.nt]=(signed char)tri_id3(j,m,n2);
      P.t_s [P.nt]=(signed char)(es*sgn3(j,m,n2));
      P.t_init[P.nt]=tinit[j]?0:1; tinit[j]=true;
      ++P.nt;
    }
  }
  for(int i=0;i<7;++i){
    if(i==k||i==l) continue;
    for(int j=i;j<7;++j){
      P.b_dst[P.nb]=(signed char)UT(i,j);
      P.b_a [P.nb]=(signed char)tri_id3(i,k,l);
      P.b_b [P.nb]=(signed char)j;
      P.b_s [P.nb]=(signed char)sgn3(i,k,l);
      ++P.nb;
    }
  }
  return P;
}

template<int G> inline constexpr GProg GP = build_group(pair_k(G), pair_l(G));

// ---------- constant-index execution ----------
template<int G,int Q>
__device__ __forceinline__ void t_step(float (&T)[7], const float (&ph)[NPHI]){
  constexpr int d=GP<G>.t_dst[Q], a=GP<G>.t_a[Q], b=GP<G>.t_b[Q];
  constexpr bool neg=(GP<G>.t_s[Q]<0), ini=(GP<G>.t_init[Q]!=0);
  const float x = neg ? -ph[a] : ph[a];
  if constexpr (ini) T[d] = x*ph[b];
  else               T[d] = fmaf(x, ph[b], T[d]);
}

template<int G,int Q>
__device__ __forceinline__ void b_step(float (&U)[28], const float (&T)[7],
                                       const float (&ph)[NPHI]){
  constexpr int d=GP<G>.b_dst[Q], a=GP<G>.b_a[Q], b=GP<G>.b_b[Q];
  constexpr bool neg=(GP<G>.b_s[Q]<0);
  const float x = neg ? -ph[a] : ph[a];
  U[d] = fmaf(x, T[b], U[d]);
}

template<int G,int... TQ>
__device__ __forceinline__ void run_t(float (&T)[7], const float (&ph)[NPHI],
                                      std::integer_sequence<int,TQ...>){
  (t_step<G,TQ>(T,ph), ...);
}
template<int G,int... BQ>
__device__ __forceinline__ void run_b(float (&U)[28], const float (&T)[7],
                                      const float (&ph)[NPHI],
                                      std::integer_sequence<int,BQ...>){
  (b_step<G,BQ>(U,T,ph), ...);
}

// Two independent elements per group region -> ILP-2 for the scheduler.
template<int G>
__device__ __forceinline__ void do_group2(float (&U0)[28], float (&U1)[28],
                                          const float (&p0)[NPHI],
                                          const float (&p1)[NPHI]){
  float T0[7], T1[7];
  run_t<G>(T0, p0, std::make_integer_sequence<int, GP<G>.nt>{});
  run_t<G>(T1, p1, std::make_integer_sequence<int, GP<G>.nt>{});
  run_b<G>(U0, T0, p0, std::make_integer_sequence<int, GP<G>.nb>{});
  run_b<G>(U1, T1, p1, std::make_integer_sequence<int, GP<G>.nb>{});
  // Fence between groups: caps live set (~170 VGPR incl. both elements),
  // spill impossible; intra-region ILP-2 preserved.
  __builtin_amdgcn_sched_barrier(0);
}

template<int... G>
__device__ __forceinline__ void all_groups2(float (&U0)[28], float (&U1)[28],
                                            const float (&p0)[NPHI],
                                            const float (&p1)[NPHI],
                                            std::integer_sequence<int,G...>){
  (do_group2<G>(U0,U1,p0,p1), ...);
}

// ---------- one Jacobi rotation (indices fold to constants after inlining) ----
__device__ __forceinline__ void jrot(float (&A)[28], int p1, int q1){
  const float apq = A[UT(p1,q1)];
  const float app = A[UT(p1,p1)];
  const float aqq = A[UT(q1,q1)];
  const float s2  = apq + apq;
  const float h   = aqq - app;
  const float r   = __builtin_amdgcn_sqrtf(fmaf(s2, s2, h*h));
  // t = sign(h)*s2/(|h|+r)  ==  s2 / (h + copysign(r, h)); eps avoids 0/0.
  const float den = h + __builtin_copysignf(r + 1e-38f, h);
  const float t   = s2 * __builtin_amdgcn_rcpf(den);
  const float c   = __builtin_amdgcn_rsqf(fmaf(t, t, 1.0f));
  const float s   = t*c;
  A[UT(p1,p1)] = fmaf(-t, apq, app);
  A[UT(q1,q1)] = fmaf( t, apq, aqq);
  A[UT(p1,q1)] = 0.0f;
  #pragma unroll
  for (int r2=0;r2<7;++r2){
    if (r2==p1 || r2==q1) continue;
    const int irp = (r2<p1)? UT(r2,p1) : UT(p1,r2);
    const int irq = (r2<q1)? UT(r2,q1) : UT(q1,r2);
    const float arp = A[irp], arq = A[irq];
    A[irp] = fmaf(c, arp, -(s*arq));
    A[irq] = fmaf(c, arq,  (s*arp));
  }
}

// ---------- epilogue: det-normalized eigenvalues -> relu sum ----------
__device__ __forceinline__ float finish(const float (&A)[28]){
  float det = 1.0f;
  #pragma unroll
  for (int i=0;i<7;++i) det *= A[UT(i,i)];
  const float ad = fabsf(det) + 1e-12f;
  const float scale = __builtin_amdgcn_exp2f(__builtin_amdgcn_logf(ad) * (1.0f/9.0f));
  const float inv = __builtin_amdgcn_rcpf(scale);
  float sum = 0.0f;
  #pragma unroll
  for (int i=0;i<7;++i){
    const float ev = A[UT(i,i)]*inv;
    sum += fmaxf(1e-6f - ev, 0.0f);
  }
  return sum;
}

// ---------- kernel: 2 elements per thread (ILP-2) ----------
__global__ __launch_bounds__(64,1)
void PositivityConstraint_89086211654295_kernel(const float* __restrict__ phi,
                                                float* __restrict__ out){
  const int gid = blockIdx.x*64 + threadIdx.x;   // 16384 threads
  const int e0 = gid;
  const int e1 = gid + BATCH/2;

  const float* __restrict__ pA = phi + (size_t)e0 * NPHI;
  const float* __restrict__ pB = phi + (size_t)e1 * NPHI;
  float ph0[NPHI], ph1[NPHI];
  #pragma unroll
  for (int i=0;i<NPHI;++i) ph0[i] = pA[i];
  #pragma unroll
  for (int i=0;i<NPHI;++i) ph1[i] = pB[i];

  float U0[28], U1[28];
  #pragma unroll
  for (int i=0;i<28;++i){ U0[i]=0.f; U1[i]=0.f; }

  all_groups2(U0, U1, ph0, ph1, std::make_integer_sequence<int,21>{});

  float A0[28], A1[28];
  #pragma unroll
  for (int i=0;i<28;++i){ A0[i]=U0[i]*(1.0f/6.0f); A1[i]=U1[i]*(1.0f/6.0f); }

  for (int sweep=0; sweep<SWEEPS; ++sweep){
    #pragma unroll
    for (int p1=0;p1<7;++p1){
      #pragma unroll
      for (int q1=p1+1;q1<7;++q1){
        jrot(A0, p1, q1);   // two independent rotation chains in one
        jrot(A1, p1, q1);   // basic block -> stalls of one fill the other
      }
    }
  }

  out[e0] = finish(A0);
  out[e1] = finish(A1);
}

// ---------- launch ----------
extern "C" void kernel_launch(void* const* d_in, const int* in_sizes, int n_in,
                              void* d_out, int out_size, void* d_ws, size_t ws_size,
                              hipStream_t stream) {
  const float* phi = (const float*)d_in[0];
  float* out = (float*)d_out;
  (void)in_sizes; (void)n_in; (void)out_size; (void)d_ws; (void)ws_size;
  hipLaunchKernelGGL(PositivityConstraint_89086211654295_kernel,
                     dim3(BATCH/2/64), dim3(64), 0, stream, phi, out);
}

// Round 5
// 67.349 us; speedup vs baseline: 1.3428x; 1.3428x over previous
//
#include <hip/hip_runtime.h>
#include <utility>

#define BATCH 32768
#define NPHI 35
#define SWEEPS 6

// ---------- compile-time combinatorics ----------
constexpr int choose2(int n){ return (n*(n-1))/2; }

constexpr int tri_id_sorted(int a,int b,int c){
  int id=0;
  for(int x=0;x<a;++x) id += choose2(6-x);
  for(int y=a+1;y<b;++y) id += (6-y);
  id += (c-b-1);
  return id;
}

constexpr int tri_id3(int a,int b,int c){
  int x=a,y=b,z=c;
  if (x>y){int t=x;x=y;y=t;}
  if (y>z){int t=y;y=z;z=t;}
  if (x>y){int t=x;x=y;y=t;}
  return tri_id_sorted(x,y,z);
}

constexpr int sgn3(int a,int b,int c){
  int inv = (a>b)+(a>c)+(b>c);
  return (inv&1)? -1 : 1;
}

constexpr int UT(int i,int j){
  return i*7 - (i*(i-1))/2 + (j-i);
}

// enumeration of the 21 (k<l) pairs; also used as Jacobi rotation order
constexpr int pair_k(int g){
  int idx=0;
  for(int k=0;k<7;++k) for(int l=k+1;l<7;++l){ if(idx==g) return k; ++idx; }
  return 0;
}
constexpr int pair_l(int g){
  int idx=0;
  for(int k=0;k<7;++k) for(int l=k+1;l<7;++l){ if(idx==g) return l; ++idx; }
  return 0;
}

// ---------- per-(k,l)-group straight-line polynomial program ----------
struct GProg {
  int nt, nb;
  signed char t_dst[50], t_a[50], t_b[50], t_s[50]; unsigned char t_init[50];
  signed char b_dst[26], b_a[26], b_b[26], b_s[26];
};

constexpr GProg build_group(int k,int l){
  GProg P{}; P.nt=0; P.nb=0;
  bool tinit[7]={};
  for(int m=0;m<7;++m) for(int n2=m+1;n2<7;++n2){
    if(m==k||m==l||n2==k||n2==l) continue;
    int comp[3]={0,0,0}; int cn=0;
    for(int x=0;x<7;++x) if(x!=k&&x!=l&&x!=m&&x!=n2){ comp[cn]=x; ++cn; }
    int perm[7]={k,l,m,n2,comp[0],comp[1],comp[2]};
    int invc=0;
    for(int i=0;i<7;++i) for(int j=i+1;j<7;++j) if(perm[i]>perm[j]) ++invc;
    const int es=(invc&1)? -1 : 1;
    const int tcomp=tri_id_sorted(comp[0],comp[1],comp[2]);
    for(int j=0;j<7;++j){
      if(j==m||j==n2) continue;
      P.t_dst[P.nt]=(signed char)j;
      P.t_a [P.nt]=(signed char)tcomp;
      P.t_b [P.nt]=(signed char)tri_id3(j,m,n2);
      P.t_s [P.nt]=(signed char)(es*sgn3(j,m,n2));
      P.t_init[P.nt]=tinit[j]?0:1; tinit[j]=true;
      ++P.nt;
    }
  }
  for(int i=0;i<7;++i){
    if(i==k||i==l) continue;
    for(int j=i;j<7;++j){
      P.b_dst[P.nb]=(signed char)UT(i,j);
      P.b_a [P.nb]=(signed char)tri_id3(i,k,l);
      P.b_b [P.nb]=(signed char)j;
      P.b_s [P.nb]=(signed char)sgn3(i,k,l);
      ++P.nb;
    }
  }
  return P;
}

template<int G> inline constexpr GProg GP = build_group(pair_k(G), pair_l(G));

// ---------- constant-index execution (poly) ----------
template<int G,int Q>
__device__ __forceinline__ void t_step(float (&T)[7], const float (&ph)[NPHI]){
  constexpr int d=GP<G>.t_dst[Q], a=GP<G>.t_a[Q], b=GP<G>.t_b[Q];
  constexpr bool neg=(GP<G>.t_s[Q]<0), ini=(GP<G>.t_init[Q]!=0);
  const float x = neg ? -ph[a] : ph[a];
  if constexpr (ini) T[d] = x*ph[b];
  else               T[d] = fmaf(x, ph[b], T[d]);
}

template<int G,int Q>
__device__ __forceinline__ void b_step(float (&U)[28], const float (&T)[7],
                                       const float (&ph)[NPHI]){
  constexpr int d=GP<G>.b_dst[Q], a=GP<G>.b_a[Q], b=GP<G>.b_b[Q];
  constexpr bool neg=(GP<G>.b_s[Q]<0);
  const float x = neg ? -ph[a] : ph[a];
  U[d] = fmaf(x, T[b], U[d]);
}

template<int G,int... TQ>
__device__ __forceinline__ void run_t(float (&T)[7], const float (&ph)[NPHI],
                                      std::integer_sequence<int,TQ...>){
  (t_step<G,TQ>(T,ph), ...);
}
template<int G,int... BQ>
__device__ __forceinline__ void run_b(float (&U)[28], const float (&T)[7],
                                      const float (&ph)[NPHI],
                                      std::integer_sequence<int,BQ...>){
  (b_step<G,BQ>(U,T,ph), ...);
}

template<int G>
__device__ __forceinline__ void do_group(float (&U)[28], const float (&ph)[NPHI]){
  float T[7];
  run_t<G>(T, ph, std::make_integer_sequence<int, GP<G>.nt>{});
  run_b<G>(U, T, ph, std::make_integer_sequence<int, GP<G>.nb>{});
  __builtin_amdgcn_sched_barrier(0);   // cap live set between groups
}

template<int... G>
__device__ __forceinline__ void all_groups(float (&U)[28], const float (&ph)[NPHI],
                                           std::integer_sequence<int,G...>){
  (do_group<G>(U,ph), ...);
}

// ---------- Jacobi rotation with TEMPLATE-CONSTANT indices ----------
// (same mechanism that fixed the poly phase in R2 — structurally impossible
//  to index A[] dynamically, so SROA must scalarize A into registers)
template<int R>
__device__ __forceinline__ void jrot_t(float (&A)[28]){
  constexpr int p1 = pair_k(R), q1 = pair_l(R);
  const float apq = A[UT(p1,q1)];
  const float app = A[UT(p1,p1)];
  const float aqq = A[UT(q1,q1)];
  const float s2  = apq + apq;
  const float h   = aqq - app;
  const float r   = __builtin_amdgcn_sqrtf(fmaf(s2, s2, h*h));
  // t = sign(h)*s2/(|h|+r) == s2/(h+copysign(r,h)); eps avoids 0/0 at apq=h=0
  const float den = h + __builtin_copysignf(r + 1e-38f, h);
  const float t   = s2 * __builtin_amdgcn_rcpf(den);
  const float c   = __builtin_amdgcn_rsqf(fmaf(t, t, 1.0f));
  const float s   = t*c;
  A[UT(p1,p1)] = fmaf(-t, apq, app);
  A[UT(q1,q1)] = fmaf( t, apq, aqq);
  A[UT(p1,q1)] = 0.0f;
  #pragma unroll
  for (int r2=0;r2<7;++r2){
    if (r2==p1 || r2==q1) continue;
    const int irp = (r2<p1)? UT(r2,p1) : UT(p1,r2);
    const int irq = (r2<q1)? UT(r2,q1) : UT(q1,r2);
    const float arp = A[irp], arq = A[irq];
    A[irp] = fmaf(c, arp, -(s*arq));
    A[irq] = fmaf(c, arq,  (s*arp));
  }
}

template<int... R>
__device__ __forceinline__ void jacobi_sweep(float (&A)[28],
                                             std::integer_sequence<int,R...>){
  (jrot_t<R>(A), ...);
}

// ---------- epilogue ----------
__device__ __forceinline__ float finish(const float (&A)[28]){
  float det = 1.0f;
  #pragma unroll
  for (int i=0;i<7;++i) det *= A[UT(i,i)];
  const float ad = fabsf(det) + 1e-12f;
  const float scale = __builtin_amdgcn_exp2f(__builtin_amdgcn_logf(ad) * (1.0f/9.0f));
  const float inv = __builtin_amdgcn_rcpf(scale);
  float sum = 0.0f;
  #pragma unroll
  for (int i=0;i<7;++i){
    const float ev = A[UT(i,i)]*inv;
    sum += fmaxf(1e-6f - ev, 0.0f);
  }
  return sum;
}

// ---------- kernel: 1 element/thread, LDS-coalesced input ----------
__global__ __launch_bounds__(64,1)
void PositivityConstraint_89086211654295_kernel(const float* __restrict__ phi,
                                                float* __restrict__ out){
  const int lane = threadIdx.x;
  const int gid  = blockIdx.x*64 + lane;

  // Coalesced stage: block covers 64 consecutive elements = 2240 contiguous
  // floats. Pad LDS rows to 36 (gcd(36,32)=4 -> lane*36 stride: 4-way groups,
  // but reads below are lane*36+k: bank=(4*lane+k)%32 — 2-way alias max, free).
  __shared__ float lph[64*36];
  const float* __restrict__ gbase = phi + (size_t)blockIdx.x * 64 * NPHI;
  #pragma unroll
  for (int i=0;i<NPHI;++i){
    const int idx = i*64 + lane;                  // coalesced dword
    lph[(idx/NPHI)*36 + (idx%NPHI)] = gbase[idx];
  }
  __syncthreads();

  float ph[NPHI];
  #pragma unroll
  for (int i=0;i<NPHI;++i) ph[i] = lph[lane*36 + i];

  float U[28];
  #pragma unroll
  for (int i=0;i<28;++i) U[i]=0.f;

  all_groups(U, ph, std::make_integer_sequence<int,21>{});

  float A[28];
  #pragma unroll
  for (int i=0;i<28;++i) A[i] = U[i]*(1.0f/6.0f);

  for (int sweep=0; sweep<SWEEPS; ++sweep){
    jacobi_sweep(A, std::make_integer_sequence<int,21>{});
  }

  out[gid] = finish(A);
}

// ---------- launch ----------
extern "C" void kernel_launch(void* const* d_in, const int* in_sizes, int n_in,
                              void* d_out, int out_size, void* d_ws, size_t ws_size,
                              hipStream_t stream) {
  const float* phi = (const float*)d_in[0];
  float* out = (float*)d_out;
  (void)in_sizes; (void)n_in; (void)out_size; (void)d_ws; (void)ws_size;
  hipLaunchKernelGGL(PositivityConstraint_89086211654295_kernel,
                     dim3(BATCH/64), dim3(64), 0, stream, phi, out);
}

// Round 6
// 66.233 us; speedup vs baseline: 1.3655x; 1.0168x over previous
//
#include <hip/hip_runtime.h>
#include <utility>

#define BATCH 32768
#define NPHI 35
#define SWEEPS 6

// ---------- compile-time combinatorics ----------
constexpr int choose2(int n){ return (n*(n-1))/2; }

constexpr int tri_id_sorted(int a,int b,int c){
  int id=0;
  for(int x=0;x<a;++x) id += choose2(6-x);
  for(int y=a+1;y<b;++y) id += (6-y);
  id += (c-b-1);
  return id;
}

constexpr int tri_id3(int a,int b,int c){
  int x=a,y=b,z=c;
  if (x>y){int t=x;x=y;y=t;}
  if (y>z){int t=y;y=z;z=t;}
  if (x>y){int t=x;x=y;y=t;}
  return tri_id_sorted(x,y,z);
}

constexpr int sgn3(int a,int b,int c){
  int inv = (a>b)+(a>c)+(b>c);
  return (inv&1)? -1 : 1;
}

constexpr int UT(int i,int j){
  return i*7 - (i*(i-1))/2 + (j-i);
}

constexpr int pair_k(int g){
  int idx=0;
  for(int k=0;k<7;++k) for(int l=k+1;l<7;++l){ if(idx==g) return k; ++idx; }
  return 0;
}
constexpr int pair_l(int g){
  int idx=0;
  for(int k=0;k<7;++k) for(int l=k+1;l<7;++l){ if(idx==g) return l; ++idx; }
  return 0;
}

// round-robin tournament: round r (0..6), slot s (0..2) -> disjoint pair
constexpr int rr_p(int r,int s){ int a=(r+1+s)%7, b=(r+6-s)%7; return a<b?a:b; }
constexpr int rr_q(int r,int s){ int a=(r+1+s)%7, b=(r+6-s)%7; return a<b?b:a; }

// ---------- per-(k,l)-group straight-line polynomial program ----------
struct GProg {
  int nt, nb;
  signed char t_dst[50], t_a[50], t_b[50], t_s[50]; unsigned char t_init[50];
  signed char b_dst[26], b_a[26], b_b[26], b_s[26];
};

constexpr GProg build_group(int k,int l){
  GProg P{}; P.nt=0; P.nb=0;
  bool tinit[7]={};
  for(int m=0;m<7;++m) for(int n2=m+1;n2<7;++n2){
    if(m==k||m==l||n2==k||n2==l) continue;
    int comp[3]={0,0,0}; int cn=0;
    for(int x=0;x<7;++x) if(x!=k&&x!=l&&x!=m&&x!=n2){ comp[cn]=x; ++cn; }
    int perm[7]={k,l,m,n2,comp[0],comp[1],comp[2]};
    int invc=0;
    for(int i=0;i<7;++i) for(int j=i+1;j<7;++j) if(perm[i]>perm[j]) ++invc;
    const int es=(invc&1)? -1 : 1;
    const int tcomp=tri_id_sorted(comp[0],comp[1],comp[2]);
    for(int j=0;j<7;++j){
      if(j==m||j==n2) continue;
      P.t_dst[P.nt]=(signed char)j;
      P.t_a [P.nt]=(signed char)tcomp;
      P.t_b [P.nt]=(signed char)tri_id3(j,m,n2);
      P.t_s [P.nt]=(signed char)(es*sgn3(j,m,n2));
      P.t_init[P.nt]=tinit[j]?0:1; tinit[j]=true;
      ++P.nt;
    }
  }
  for(int i=0;i<7;++i){
    if(i==k||i==l) continue;
    for(int j=i;j<7;++j){
      P.b_dst[P.nb]=(signed char)UT(i,j);
      P.b_a [P.nb]=(signed char)tri_id3(i,k,l);
      P.b_b [P.nb]=(signed char)j;
      P.b_s [P.nb]=(signed char)sgn3(i,k,l);
      ++P.nb;
    }
  }
  return P;
}

template<int G> inline constexpr GProg GP = build_group(pair_k(G), pair_l(G));

// ---------- constant-index execution (poly) ----------
template<int G,int Q>
__device__ __forceinline__ void t_step(float (&T)[7], const float (&ph)[NPHI]){
  constexpr int d=GP<G>.t_dst[Q], a=GP<G>.t_a[Q], b=GP<G>.t_b[Q];
  constexpr bool neg=(GP<G>.t_s[Q]<0), ini=(GP<G>.t_init[Q]!=0);
  const float x = neg ? -ph[a] : ph[a];
  if constexpr (ini) T[d] = x*ph[b];
  else               T[d] = fmaf(x, ph[b], T[d]);
}

template<int G,int Q>
__device__ __forceinline__ void b_step(float (&U)[28], const float (&T)[7],
                                       const float (&ph)[NPHI]){
  constexpr int d=GP<G>.b_dst[Q], a=GP<G>.b_a[Q], b=GP<G>.b_b[Q];
  constexpr bool neg=(GP<G>.b_s[Q]<0);
  const float x = neg ? -ph[a] : ph[a];
  U[d] = fmaf(x, T[b], U[d]);
}

template<int G,int... TQ>
__device__ __forceinline__ void run_t(float (&T)[7], const float (&ph)[NPHI],
                                      std::integer_sequence<int,TQ...>){
  (t_step<G,TQ>(T,ph), ...);
}
template<int G,int... BQ>
__device__ __forceinline__ void run_b(float (&U)[28], const float (&T)[7],
                                      const float (&ph)[NPHI],
                                      std::integer_sequence<int,BQ...>){
  (b_step<G,BQ>(U,T,ph), ...);
}

template<int G>
__device__ __forceinline__ void do_group(float (&U)[28], const float (&ph)[NPHI]){
  float T[7];
  run_t<G>(T, ph, std::make_integer_sequence<int, GP<G>.nt>{});
  run_b<G>(U, T, ph, std::make_integer_sequence<int, GP<G>.nb>{});
  __builtin_amdgcn_sched_barrier(0);   // cap live set between groups
}

template<int... G>
__device__ __forceinline__ void all_groups(float (&U)[28], const float (&ph)[NPHI],
                                           std::integer_sequence<int,G...>){
  (do_group<G>(U,ph), ...);
}

// ---------- parallel-ordered Jacobi: 7 rounds x 3 independent rotations ------
template<int P,int Q>
__device__ __forceinline__ void jangle(const float (&A)[28],
                                       float &t, float &c, float &s){
  const float apq = A[UT(P,Q)];
  const float app = A[UT(P,P)];
  const float aqq = A[UT(Q,Q)];
  const float s2  = apq + apq;
  const float h   = aqq - app;
  const float r   = __builtin_amdgcn_sqrtf(fmaf(s2, s2, h*h));
  const float den = h + __builtin_copysignf(r + 1e-38f, h);
  t = s2 * __builtin_amdgcn_rcpf(den);
  c = __builtin_amdgcn_rsqf(fmaf(t, t, 1.0f));
  s = t*c;
}

template<int P,int Q>
__device__ __forceinline__ void japply(float (&A)[28], float t, float c, float s){
  const float apq = A[UT(P,Q)];
  A[UT(P,P)] = fmaf(-t, apq, A[UT(P,P)]);
  A[UT(Q,Q)] = fmaf( t, apq, A[UT(Q,Q)]);
  A[UT(P,Q)] = 0.0f;
  #pragma unroll
  for (int r2=0;r2<7;++r2){
    if (r2==P || r2==Q) continue;
    const int irp = (r2<P)? UT(r2,P) : UT(P,r2);
    const int irq = (r2<Q)? UT(r2,Q) : UT(Q,r2);
    const float arp = A[irp], arq = A[irq];
    A[irp] = fmaf(c, arp, -(s*arq));
    A[irq] = fmaf(c, arq,  (s*arp));
  }
}

template<int R>
__device__ __forceinline__ void jround(float (&A)[28]){
  constexpr int p0=rr_p(R,0), q0=rr_q(R,0);
  constexpr int p1=rr_p(R,1), q1=rr_q(R,1);
  constexpr int p2=rr_p(R,2), q2=rr_q(R,2);
  // Angle inputs (pivot + two diagonals) of the 3 disjoint-plane rotations
  // are mutually untouched -> compute all 3 chains first (ILP-3), then apply.
  float t0,c0,s0, t1,c1,s1, t2,c2,s2;
  jangle<p0,q0>(A, t0,c0,s0);
  jangle<p1,q1>(A, t1,c1,s1);
  jangle<p2,q2>(A, t2,c2,s2);
  japply<p0,q0>(A, t0,c0,s0);
  japply<p1,q1>(A, t1,c1,s1);
  japply<p2,q2>(A, t2,c2,s2);
}

template<int... R>
__device__ __forceinline__ void jsweep(float (&A)[28],
                                       std::integer_sequence<int,R...>){
  (jround<R>(A), ...);
}

// ---------- epilogue ----------
__device__ __forceinline__ float finish(const float (&A)[28]){
  float det = 1.0f;
  #pragma unroll
  for (int i=0;i<7;++i) det *= A[UT(i,i)];
  const float ad = fabsf(det) + 1e-12f;
  const float scale = __builtin_amdgcn_exp2f(__builtin_amdgcn_logf(ad) * (1.0f/9.0f));
  const float inv = __builtin_amdgcn_rcpf(scale);
  float sum = 0.0f;
  #pragma unroll
  for (int i=0;i<7;++i){
    const float ev = A[UT(i,i)]*inv;
    sum += fmaxf(1e-6f - ev, 0.0f);
  }
  return sum;
}

// ---------- kernel: 1 element/thread, LDS-coalesced input ----------
__global__ __launch_bounds__(64,1)
void PositivityConstraint_89086211654295_kernel(const float* __restrict__ phi,
                                                float* __restrict__ out){
  const int lane = threadIdx.x;
  const int gid  = blockIdx.x*64 + lane;

  __shared__ float lph[64*36];
  const float* __restrict__ gbase = phi + (size_t)blockIdx.x * 64 * NPHI;
  #pragma unroll
  for (int i=0;i<NPHI;++i){
    const int idx = i*64 + lane;                  // coalesced dword
    lph[(idx/NPHI)*36 + (idx%NPHI)] = gbase[idx];
  }
  __syncthreads();

  float ph[NPHI];
  #pragma unroll
  for (int i=0;i<NPHI;++i) ph[i] = lph[lane*36 + i];

  float U[28];
  #pragma unroll
  for (int i=0;i<28;++i) U[i]=0.f;

  all_groups(U, ph, std::make_integer_sequence<int,21>{});

  float A[28];
  #pragma unroll
  for (int i=0;i<28;++i) A[i] = U[i]*(1.0f/6.0f);

  for (int sweep=0; sweep<SWEEPS; ++sweep){
    jsweep(A, std::make_integer_sequence<int,7>{});
  }

  out[gid] = finish(A);
}

// ---------- launch ----------
extern "C" void kernel_launch(void* const* d_in, const int* in_sizes, int n_in,
                              void* d_out, int out_size, void* d_ws, size_t ws_size,
                              hipStream_t stream) {
  const float* phi = (const float*)d_in[0];
  float* out = (float*)d_out;
  (void)in_sizes; (void)n_in; (void)out_size; (void)d_ws; (void)ws_size;
  hipLaunchKernelGGL(PositivityConstraint_89086211654295_kernel,
                     dim3(BATCH/64), dim3(64), 0, stream, phi, out);
}